// Round 1
// baseline (915.953 us; speedup 1.0000x reference)
//
#include <hip/hip_runtime.h>

// Fused Swin shifted-window MSA, one workgroup per 7x7 window.
// B=32, H=W=56, C=128, NH=4, hd=32, WS=7, SS=3 -> 2048 windows, N=49 tokens.
// Round 1: correctness-first, f32 VALU (no MFMA). Validates shift/window/mask/
// bias indexing end-to-end; MFMA phases come next round on this skeleton.

#define WSZ   7
#define SSZ   3
#define NHEAD 4
#define HDIM  32
#define CDIM  128
#define NPIX  49
#define HWDIM 56
#define SCALE_Q 0.17677669529663687f   // 1/sqrt(32)

__device__ __forceinline__ unsigned short f2bf(float f) {
    unsigned u = __float_as_uint(f);
    u += 0x7fffu + ((u >> 16) & 1u);     // RNE
    return (unsigned short)(u >> 16);
}
__device__ __forceinline__ float bflo(unsigned u) { return __uint_as_float(u << 16); }
__device__ __forceinline__ float bfhi(unsigned u) { return __uint_as_float(u & 0xffff0000u); }

// transpose weights once per launch: Wt[k][col] = W[col][k]
__global__ void prep_transpose(const float* __restrict__ w_qkv,
                               const float* __restrict__ w_proj,
                               float* __restrict__ wqkv_t,    // [128][384]
                               float* __restrict__ wproj_t)   // [128][128]
{
    int idx = blockIdx.x * blockDim.x + threadIdx.x;
    if (idx < 384 * 128) {
        int k = idx / 384, cw = idx % 384;
        wqkv_t[idx] = w_qkv[cw * 128 + k];
    } else {
        int j = idx - 384 * 128;
        if (j < 128 * 128) {
            int k = j / 128, cc = j % 128;
            wproj_t[j] = w_proj[cc * 128 + k];
        }
    }
}

__global__ __launch_bounds__(256, 2)
void swin_msa_fused(const float* __restrict__ x,
                    const float* __restrict__ rpb,
                    const float* __restrict__ wqkv_t,
                    const float* __restrict__ wproj_t,
                    const float* __restrict__ b_proj,
                    float* __restrict__ out)
{
    // LDS: Xs (f32, reused as attention-out O) + QKV staged bf16 (stride 130
    // shorts -> per-lane row reads hit distinct banks). Total 63,308 B.
    __shared__ __align__(16) float Xs[NPIX * CDIM];                 // 25088 B
    __shared__ __align__(16) unsigned short QKVs[3 * NPIX * 130];   // 38220 B

    const int tid  = threadIdx.x;
    const int blk  = blockIdx.x;
    const int b    = blk >> 6;        // batch
    const int wIdx = blk & 63;
    const int wh   = wIdx >> 3, ww = wIdx & 7;

    // ---- phase 1: load cyclically-shifted window (roll by -3 => src = p+3 mod 56)
    for (int idx = tid; idx < NPIX * CDIM; idx += 256) {
        int p  = idx >> 7;            // token 0..48
        int ch = idx & 127;
        int rr = p / 7, cc = p % 7;
        int sh = wh * 7 + rr + SSZ; if (sh >= HWDIM) sh -= HWDIM;
        int sw = ww * 7 + cc + SSZ; if (sw >= HWDIM) sw -= HWDIM;
        Xs[idx] = x[((b * HWDIM + sh) * HWDIM + sw) * CDIM + ch];
    }
    __syncthreads();

    // ---- phase 2: QKV = Xs @ Wqkv^T, q pre-scaled, stored bf16
    {
        const int c = tid & 127;      // output channel within q/k/v
        const int s = tid >> 7;       // row-half (wave-uniform)
        const int rbase = s * 25;
        for (int m = 0; m < 3; ++m) {
            float acc[25];
            #pragma unroll
            for (int j = 0; j < 25; ++j) acc[j] = 0.f;
            const float* W = wqkv_t + m * 128 + c;
            for (int k4 = 0; k4 < 32; ++k4) {
                const float w0 = W[(k4 * 4 + 0) * 384];
                const float w1 = W[(k4 * 4 + 1) * 384];
                const float w2 = W[(k4 * 4 + 2) * 384];
                const float w3 = W[(k4 * 4 + 3) * 384];
                #pragma unroll
                for (int j = 0; j < 25; ++j) {
                    if (rbase + j < NPIX) {   // broadcast LDS read (wave-uniform addr)
                        const float4 xv = *(const float4*)&Xs[(rbase + j) * CDIM + k4 * 4];
                        acc[j] = fmaf(xv.w, w3, fmaf(xv.z, w2, fmaf(xv.y, w1, fmaf(xv.x, w0, acc[j]))));
                    }
                }
            }
            const float sc = (m == 0) ? SCALE_Q : 1.0f;
            #pragma unroll
            for (int j = 0; j < 25; ++j) {
                int r = rbase + j;
                if (r < NPIX) QKVs[m * (NPIX * 130) + r * 130 + c] = f2bf(acc[j] * sc);
            }
        }
    }
    __syncthreads();

    // ---- phase 3+4: per-head attention (wave h), O written into Xs region
    {
        const int h = tid >> 6;
        const int l = tid & 63;       // lane; l<49 owns key/token j=l
        const unsigned* Q32 = (const unsigned*)QKVs;   // 65 uints per row
        int rj = 0, cj = 0, gj = 0;
        if (l < NPIX) {
            rj = l / 7; cj = l % 7;
            int sh = wh * 7 + rj, sw = ww * 7 + cj;
            int rz = (sh < 49) ? 0 : (sh < 53 ? 1 : 2);
            int cz = (sw < 49) ? 0 : (sw < 53 ? 1 : 2);
            gj = rz * 3 + cz;         // shift-mask group id
        }
        const int d    = l & 31;
        const int half = l >> 5;
        const unsigned qbase = 0 * 3185 + (unsigned)(h * 16);
        const unsigned kbase = 1 * 3185 + (unsigned)(h * 16);
        const unsigned vbase = 2 * 3185 + (unsigned)(h * 16);

        for (int i = 0; i < NPIX; ++i) {
            float sv = -1e30f;
            if (l < NPIX) {
                float acc = 0.f;
                #pragma unroll
                for (int d2 = 0; d2 < 16; ++d2) {
                    unsigned uq = Q32[qbase + (unsigned)(i * 65 + d2)];   // broadcast
                    unsigned uk = Q32[kbase + (unsigned)(l * 65 + d2)];   // per-lane row
                    acc = fmaf(bflo(uq), bflo(uk), acc);
                    acc = fmaf(bfhi(uq), bfhi(uk), acc);
                }
                int ri = i / 7, ci = i % 7;
                int rel = (ri - rj + 6) * 13 + (ci - cj + 6);
                acc += rpb[rel * NHEAD + h];
                sv = acc;
            }
            int gi = __shfl(gj, i);
            if (l < NPIX && gi != gj) sv -= 100.0f;
            // softmax across lanes (j axis)
            float mx = sv;
            #pragma unroll
            for (int off = 32; off > 0; off >>= 1) mx = fmaxf(mx, __shfl_xor(mx, off));
            float e = (l < NPIX) ? __expf(sv - mx) : 0.f;
            float sum = e;
            #pragma unroll
            for (int off = 32; off > 0; off >>= 1) sum += __shfl_xor(sum, off);
            float pr = e / sum;
            // PV: lanes = (d, j-half); redistribute p via shfl
            float acc = 0.f;
            #pragma unroll
            for (int jj = 0; jj < 25; ++jj) {
                int j2 = half * 25 + jj;
                int j2c = (j2 < NPIX) ? j2 : 0;
                float pj = __shfl(pr, j2c);                 // non-divergent
                unsigned uv = Q32[vbase + (unsigned)(j2c * 65 + (d >> 1))];
                float vv = (d & 1) ? bfhi(uv) : bflo(uv);
                if (j2 < NPIX) acc = fmaf(pj, vv, acc);
            }
            acc += __shfl_xor(acc, 32);                     // combine j-halves
            if (l < 32) Xs[i * CDIM + h * HDIM + l] = acc;  // O[i][h*32+d]
        }
    }
    __syncthreads();

    // ---- phase 5: out = O @ Wproj^T + b, scatter with inverse shift
    {
        const int c = tid & 127;
        const int s = tid >> 7;
        const int rbase = s * 25;
        float acc[25];
        #pragma unroll
        for (int j = 0; j < 25; ++j) acc[j] = 0.f;
        const float* W = wproj_t + c;
        for (int k4 = 0; k4 < 32; ++k4) {
            const float w0 = W[(k4 * 4 + 0) * 128];
            const float w1 = W[(k4 * 4 + 1) * 128];
            const float w2 = W[(k4 * 4 + 2) * 128];
            const float w3 = W[(k4 * 4 + 3) * 128];
            #pragma unroll
            for (int j = 0; j < 25; ++j) {
                if (rbase + j < NPIX) {
                    const float4 xv = *(const float4*)&Xs[(rbase + j) * CDIM + k4 * 4];
                    acc[j] = fmaf(xv.w, w3, fmaf(xv.z, w2, fmaf(xv.y, w1, fmaf(xv.x, w0, acc[j]))));
                }
            }
        }
        const float bias = b_proj[c];
        #pragma unroll
        for (int j = 0; j < 25; ++j) {
            int p = rbase + j;
            if (p < NPIX) {
                int rr = p / 7, cc = p % 7;
                int sh = wh * 7 + rr + SSZ; if (sh >= HWDIM) sh -= HWDIM;
                int sw = ww * 7 + cc + SSZ; if (sw >= HWDIM) sw -= HWDIM;
                out[((b * HWDIM + sh) * HWDIM + sw) * CDIM + c] = acc[j] + bias;
            }
        }
    }
}

extern "C" void kernel_launch(void* const* d_in, const int* in_sizes, int n_in,
                              void* d_out, int out_size, void* d_ws, size_t ws_size,
                              hipStream_t stream) {
    const float* x     = (const float*)d_in[0];
    const float* rpb   = (const float*)d_in[1];
    const float* wqkv  = (const float*)d_in[2];
    const float* wproj = (const float*)d_in[3];
    const float* bproj = (const float*)d_in[4];
    float* outp = (float*)d_out;

    float* wqkv_t  = (float*)d_ws;            // 128*384 f32
    float* wproj_t = wqkv_t + 384 * 128;      // 128*128 f32

    prep_transpose<<<256, 256, 0, stream>>>(wqkv, wproj, wqkv_t, wproj_t);
    swin_msa_fused<<<32 * 64, 256, 0, stream>>>(x, rpb, wqkv_t, wproj_t, bproj, outp);
}

// Round 3
// 101.117 us; speedup vs baseline: 9.0584x; 9.0584x over previous
//
#include <hip/hip_runtime.h>

// Fused Swin shifted-window MSA, one workgroup (4 waves) per 7x7 window.
// Round 3: round-2 MFMA kernel with cvt_pkrtz return-type fix (__fp16 vec2).
// B=32, H=W=56, C=128, NH=4, hd=32 -> 2048 windows of N=49 tokens (padded to 64).

#define HWD 56
#define SCALE_Q 0.17677669529663687f   // 1/sqrt(32)

typedef _Float16 f16x8 __attribute__((ext_vector_type(8)));
typedef __fp16   h16x2 __attribute__((ext_vector_type(2)));   // cvt_pkrtz return type
typedef float    f32x4 __attribute__((ext_vector_type(4)));

__device__ __forceinline__ unsigned pkrtz(float a, float b) {
    union { h16x2 h; unsigned u; } r;
    r.h = __builtin_amdgcn_cvt_pkrtz(a, b);
    return r.u;
}

__device__ __forceinline__ f32x4 mfma16(const unsigned a[4], const unsigned b[4], f32x4 c) {
    union { unsigned u[4]; f16x8 h; } A, B;
    A.u[0] = a[0]; A.u[1] = a[1]; A.u[2] = a[2]; A.u[3] = a[3];
    B.u[0] = b[0]; B.u[1] = b[1]; B.u[2] = b[2]; B.u[3] = b[3];
    return __builtin_amdgcn_mfma_f32_16x16x32_f16(A.h, B.h, c, 0, 0, 0);
}

// biasF[wtype][head][j][i] : rel-pos bias + shift mask + key-padding mask, 4*4*64*64 f32
__global__ void prep_bias(const float* __restrict__ rpb, float* __restrict__ biasF) {
    int idx = blockIdx.x * 256 + threadIdx.x;          // 65536 elems
    int i = idx & 63, j = (idx >> 6) & 63, h = (idx >> 12) & 3, t = idx >> 14;
    float v;
    if (j >= 49)       v = -1e30f;                     // key padding
    else if (i >= 49)  v = 0.f;                        // query padding (don't care)
    else {
        int ri = i / 7, ci = i % 7, rj = j / 7, cj = j % 7;
        int rel = (ri - rj + 6) * 13 + (ci - cj + 6);
        v = rpb[rel * 4 + h];
        int gi = ((t & 2) ? (ri < 4 ? 1 : 2) : 0) * 3 + ((t & 1) ? (ci < 4 ? 1 : 2) : 0);
        int gj = ((t & 2) ? (rj < 4 ? 1 : 2) : 0) * 3 + ((t & 1) ? (cj < 4 ? 1 : 2) : 0);
        if (gi != gj) v -= 100.f;                      // shift mask (matches ref -100)
    }
    biasF[idx] = v;
}

__global__ __launch_bounds__(256, 2)
void swin_msa_mfma(const float* __restrict__ x,
                   const float* __restrict__ w_qkv,
                   const float* __restrict__ w_proj,
                   const float* __restrict__ b_proj,
                   const float* __restrict__ biasF,
                   float* __restrict__ out)
{
    // QKO: f16 [tok 0..63][qk-col 0..255], stride 264 halves (528B: 16B-aligned rows,
    //      word-stride==4 mod 32 -> uniform bank use). Reused later as O [tok][d] stride 136.
    // VT : f16 V^T [d 0..127][tok 0..63], stride 72 halves (144B).
    __shared__ __align__(16) unsigned short QKO[64 * 264];   // 33792 B
    __shared__ __align__(16) unsigned short VT[128 * 72];    // 18432 B

    const int tid  = threadIdx.x;
    const int w    = tid >> 6;         // wave id (= head in attention)
    const int lane = tid & 63;
    const int c    = lane & 15;
    const int g    = lane >> 4;

    const int blk  = blockIdx.x;
    const int b    = blk >> 6;
    const int wIdx = blk & 63;
    const int wh   = wIdx >> 3, ww = wIdx & 7;
    const int wtype = ((wh == 7) ? 2 : 0) | ((ww == 7) ? 1 : 0);

    auto tokAddr = [&](int tok) {      // tok must be < 49
        int rr = tok / 7, cc = tok - rr * 7;
        int sh = wh * 7 + rr + 3; if (sh >= HWD) sh -= HWD;
        int sw = ww * 7 + cc + 3; if (sw >= HWD) sw -= HWD;
        return ((b * HWD + sh) * HWD + sw) * 128;
    };

    // ================= phase A: QKV = X @ Wqkv^T =================
    // X-frags: serve as A (X[tok=c][k]) and B (X[tok=c][k]) -- identical content.
    unsigned xf[4][4][4];              // [tok-tile][kstep][word]
    #pragma unroll
    for (int nt = 0; nt < 4; ++nt) {
        int tok = nt * 16 + c; if (tok > 48) tok = 48;      // clamp pad rows (finite dup)
        const float* xr = x + tokAddr(tok) + g * 8;
        #pragma unroll
        for (int kk = 0; kk < 4; ++kk) {
            float4 lo = *(const float4*)(xr + kk * 32);
            float4 hi = *(const float4*)(xr + kk * 32 + 4);
            xf[nt][kk][0] = pkrtz(lo.x, lo.y);
            xf[nt][kk][1] = pkrtz(lo.z, lo.w);
            xf[nt][kk][2] = pkrtz(hi.x, hi.y);
            xf[nt][kk][3] = pkrtz(hi.z, hi.w);
        }
    }

    // --- Q,K (cols 0..255): mfma(A=W, B=X) -> D[qkcol][tok] -> row-major [tok][col] store
    #pragma unroll
    for (int mi = 0; mi < 4; ++mi) {
        const int mt = 4 * w + mi;                          // col-tile 0..15 (q:0-7, k:8-15)
        const float scale = (mt < 8) ? SCALE_Q : 1.0f;
        unsigned af[4][4];
        const float* wr = w_qkv + (mt * 16 + c) * 128 + g * 8;
        #pragma unroll
        for (int kk = 0; kk < 4; ++kk) {
            float4 lo = *(const float4*)(wr + kk * 32);
            float4 hi = *(const float4*)(wr + kk * 32 + 4);
            af[kk][0] = pkrtz(lo.x, lo.y); af[kk][1] = pkrtz(lo.z, lo.w);
            af[kk][2] = pkrtz(hi.x, hi.y); af[kk][3] = pkrtz(hi.z, hi.w);
        }
        #pragma unroll
        for (int nt = 0; nt < 4; ++nt) {
            f32x4 acc = {0.f, 0.f, 0.f, 0.f};
            #pragma unroll
            for (int kk = 0; kk < 4; ++kk) acc = mfma16(af[kk], xf[nt][kk], acc);
            unsigned d0 = pkrtz(acc[0] * scale, acc[1] * scale);
            unsigned d1 = pkrtz(acc[2] * scale, acc[3] * scale);
            // lane: tok = nt*16+c, cols mt*16+4g..+3
            *(uint2*)&QKO[(nt * 16 + c) * 264 + mt * 16 + 4 * g] = make_uint2(d0, d1);
        }
    }
    // --- V (cols 256..383): mfma(A=X, B=W) -> D[tok][vcol] -> V^T[d][tok] store
    #pragma unroll
    for (int vi = 0; vi < 2; ++vi) {
        const int vt = 2 * w + vi;                          // v col-tile 0..7 (d = vt*16+c)
        unsigned bf[4][4];
        const float* wr = w_qkv + (256 + vt * 16 + c) * 128 + g * 8;
        #pragma unroll
        for (int kk = 0; kk < 4; ++kk) {
            float4 lo = *(const float4*)(wr + kk * 32);
            float4 hi = *(const float4*)(wr + kk * 32 + 4);
            bf[kk][0] = pkrtz(lo.x, lo.y); bf[kk][1] = pkrtz(lo.z, lo.w);
            bf[kk][2] = pkrtz(hi.x, hi.y); bf[kk][3] = pkrtz(hi.z, hi.w);
        }
        #pragma unroll
        for (int mt = 0; mt < 4; ++mt) {
            f32x4 acc = {0.f, 0.f, 0.f, 0.f};
            #pragma unroll
            for (int kk = 0; kk < 4; ++kk) acc = mfma16(xf[mt][kk], bf[kk], acc);
            unsigned d0 = pkrtz(acc[0], acc[1]);
            unsigned d1 = pkrtz(acc[2], acc[3]);
            // lane: d = vt*16+c, toks mt*16+4g..+3
            *(uint2*)&VT[(vt * 16 + c) * 72 + mt * 16 + 4 * g] = make_uint2(d0, d1);
        }
    }
    __syncthreads();

    // ================= attention: wave = head h =================
    const int h = w;
    unsigned kA[4][4], qB[4][4];
    #pragma unroll
    for (int mt = 0; mt < 4; ++mt) {   // A = K[j][d]
        uint4 v = *(const uint4*)&QKO[(mt * 16 + c) * 264 + 128 + h * 32 + g * 8];
        kA[mt][0] = v.x; kA[mt][1] = v.y; kA[mt][2] = v.z; kA[mt][3] = v.w;
    }
    #pragma unroll
    for (int nt = 0; nt < 4; ++nt) {   // B = Q^T: B[d][i] from Q[i][d]
        uint4 v = *(const uint4*)&QKO[(nt * 16 + c) * 264 + h * 32 + g * 8];
        qB[nt][0] = v.x; qB[nt][1] = v.y; qB[nt][2] = v.z; qB[nt][3] = v.w;
    }
    f32x4 S[4][4];                     // S^T tiles: [j-tile mt][i-tile nt]; lane: j=16mt+4g+r, i=16nt+c
    #pragma unroll
    for (int mt = 0; mt < 4; ++mt)
        #pragma unroll
        for (int nt = 0; nt < 4; ++nt) {
            f32x4 z = {0.f, 0.f, 0.f, 0.f};
            S[mt][nt] = mfma16(kA[mt], qB[nt], z);
        }

    // bias + shift mask + padding mask (precomputed table)
    const float* bF = biasF + (wtype * 4 + h) * 4096;       // [j][i]
    #pragma unroll
    for (int mt = 0; mt < 4; ++mt)
        #pragma unroll
        for (int r = 0; r < 4; ++r) {
            const float* row = bF + (mt * 16 + 4 * g + r) * 64;
            #pragma unroll
            for (int nt = 0; nt < 4; ++nt)
                S[mt][nt][r] += row[nt * 16 + c];
        }

    // softmax over j (16 in-lane values + butterfly over the 4 lane-groups)
    float inv[4];
    #pragma unroll
    for (int nt = 0; nt < 4; ++nt) {
        float m = -1e30f;
        #pragma unroll
        for (int mt = 0; mt < 4; ++mt)
            #pragma unroll
            for (int r = 0; r < 4; ++r) m = fmaxf(m, S[mt][nt][r]);
        m = fmaxf(m, __shfl_xor(m, 16));
        m = fmaxf(m, __shfl_xor(m, 32));
        float s = 0.f;
        #pragma unroll
        for (int mt = 0; mt < 4; ++mt)
            #pragma unroll
            for (int r = 0; r < 4; ++r) {
                float e = __expf(S[mt][nt][r] - m);
                S[mt][nt][r] = e;
                s += e;
            }
        s += __shfl_xor(s, 16);
        s += __shfl_xor(s, 32);
        inv[nt] = 1.0f / s;
    }

    // V^T frags: A[m=d][k=j]
    unsigned vA[2][2][4];
    #pragma unroll
    for (int dn = 0; dn < 2; ++dn)
        #pragma unroll
        for (int kv = 0; kv < 2; ++kv) {
            uint4 v = *(const uint4*)&VT[(h * 32 + dn * 16 + c) * 72 + kv * 32 + g * 8];
            vA[dn][kv][0] = v.x; vA[dn][kv][1] = v.y; vA[dn][kv][2] = v.z; vA[dn][kv][3] = v.w;
        }

    // PV: redistribute P^T regs -> B-frag layout via shuffles, mfma(V^T, P) -> O[i][d]
    f32x4 O[4][2];
    #pragma unroll
    for (int nt = 0; nt < 4; ++nt)
        #pragma unroll
        for (int dn = 0; dn < 2; ++dn) { f32x4 z = {0.f,0.f,0.f,0.f}; O[nt][dn] = z; }

    const int srcA = c | ((lane & 16) << 1);   // lane (c, 2*(g&1))
    const int srcB = srcA + 16;                // lane (c, 2*(g&1)+1)
    const bool hiSel = (lane & 32) != 0;       // g>>1 selects mt-pair member
    #pragma unroll
    for (int nt = 0; nt < 4; ++nt) {
        const float iv = inv[nt];
        unsigned pk[4][2];
        #pragma unroll
        for (int mt = 0; mt < 4; ++mt) {
            pk[mt][0] = pkrtz(S[mt][nt][0] * iv, S[mt][nt][1] * iv);
            pk[mt][1] = pkrtz(S[mt][nt][2] * iv, S[mt][nt][3] * iv);
        }
        #pragma unroll
        for (int kk = 0; kk < 2; ++kk) {
            unsigned pB[4];
            #pragma unroll
            for (int p = 0; p < 2; ++p) {
                unsigned lo0 = __shfl(pk[2 * kk][p],     srcA);
                unsigned hi0 = __shfl(pk[2 * kk + 1][p], srcA);
                pB[p]     = hiSel ? hi0 : lo0;
                unsigned lo1 = __shfl(pk[2 * kk][p],     srcB);
                unsigned hi1 = __shfl(pk[2 * kk + 1][p], srcB);
                pB[2 + p] = hiSel ? hi1 : lo1;
            }
            #pragma unroll
            for (int dn = 0; dn < 2; ++dn)
                O[nt][dn] = mfma16(vA[dn][kk], pB, O[nt][dn]);
        }
    }
    __syncthreads();    // all QKO reads done -> safe to overlay O

    // O store: lane holds i = nt*16+c, d = h*32+dn*16+4g..+3 -> row-major [tok][d] stride 136
    #pragma unroll
    for (int nt = 0; nt < 4; ++nt)
        #pragma unroll
        for (int dn = 0; dn < 2; ++dn) {
            unsigned d0 = pkrtz(O[nt][dn][0], O[nt][dn][1]);
            unsigned d1 = pkrtz(O[nt][dn][2], O[nt][dn][3]);
            *(uint2*)&QKO[(nt * 16 + c) * 136 + h * 32 + dn * 16 + 4 * g] = make_uint2(d0, d1);
        }
    __syncthreads();

    // ================= out-proj: OUT = O @ Wproj^T + b =================
    int taddr[4];
    #pragma unroll
    for (int nt = 0; nt < 4; ++nt) {
        int tok = nt * 16 + c;
        taddr[nt] = (tok < 49) ? tokAddr(tok) : -1;
    }
    unsigned oB[4][4][4];              // B[k=d][n=i] from O[i][d]
    #pragma unroll
    for (int nt = 0; nt < 4; ++nt)
        #pragma unroll
        for (int kk = 0; kk < 4; ++kk) {
            uint4 v = *(const uint4*)&QKO[(nt * 16 + c) * 136 + kk * 32 + g * 8];
            oB[nt][kk][0] = v.x; oB[nt][kk][1] = v.y; oB[nt][kk][2] = v.z; oB[nt][kk][3] = v.w;
        }
    #pragma unroll
    for (int mi = 0; mi < 2; ++mi) {
        const int mt = 2 * w + mi;                          // out-col tile 0..7
        unsigned aW[4][4];
        const float* wr = w_proj + (mt * 16 + c) * 128 + g * 8;
        #pragma unroll
        for (int kk = 0; kk < 4; ++kk) {
            float4 lo = *(const float4*)(wr + kk * 32);
            float4 hi = *(const float4*)(wr + kk * 32 + 4);
            aW[kk][0] = pkrtz(lo.x, lo.y); aW[kk][1] = pkrtz(lo.z, lo.w);
            aW[kk][2] = pkrtz(hi.x, hi.y); aW[kk][3] = pkrtz(hi.z, hi.w);
        }
        float4 bias4 = *(const float4*)(b_proj + mt * 16 + 4 * g);
        #pragma unroll
        for (int nt = 0; nt < 4; ++nt) {
            f32x4 acc = {0.f, 0.f, 0.f, 0.f};
            #pragma unroll
            for (int kk = 0; kk < 4; ++kk) acc = mfma16(aW[kk], oB[nt][kk], acc);
            if (taddr[nt] >= 0) {
                float4 o = make_float4(acc[0] + bias4.x, acc[1] + bias4.y,
                                       acc[2] + bias4.z, acc[3] + bias4.w);
                *(float4*)(out + taddr[nt] + mt * 16 + 4 * g) = o;
            }
        }
    }
}

extern "C" void kernel_launch(void* const* d_in, const int* in_sizes, int n_in,
                              void* d_out, int out_size, void* d_ws, size_t ws_size,
                              hipStream_t stream) {
    const float* x     = (const float*)d_in[0];
    const float* rpb   = (const float*)d_in[1];
    const float* wqkv  = (const float*)d_in[2];
    const float* wproj = (const float*)d_in[3];
    const float* bproj = (const float*)d_in[4];
    float* outp = (float*)d_out;

    float* biasF = (float*)d_ws;       // 4*4*64*64 f32 = 256 KB

    prep_bias<<<256, 256, 0, stream>>>(rpb, biasF);
    swin_msa_mfma<<<32 * 64, 256, 0, stream>>>(x, wqkv, wproj, bproj, biasF, outp);
}

// Round 4
// 87.842 us; speedup vs baseline: 10.4273x; 1.1511x over previous
//
#include <hip/hip_runtime.h>

// Fused Swin shifted-window MSA, one workgroup (4 waves) per 7x7 window.
// Round 4: occupancy + dependency-chain attack.
//  - prep kernel pre-converts weights to f16 (q pre-scaled) and builds a
//    TRANSPOSED bias table [wtype][h][i][j] so bias loads are float4 and get
//    folded into the QK^T MFMA C-operand (no VALU adds).
//  - V never touches LDS: redistributed D->A-frag in registers with the same
//    shuffle template used for P (proven in round 3). LDS 52.2KB -> 33.8KB
//    => 4 blocks/CU.
//  - attention fused per-i-tile (S footprint 16 f32, not 64).

#define HWD 56
#define SCALE_Q 0.17677669529663687f   // 1/sqrt(32)

typedef _Float16 f16x8 __attribute__((ext_vector_type(8)));
typedef __fp16   h16x2 __attribute__((ext_vector_type(2)));   // cvt_pkrtz return type
typedef float    f32x4 __attribute__((ext_vector_type(4)));

__device__ __forceinline__ unsigned pkrtz(float a, float b) {
    union { h16x2 h; unsigned u; } r;
    r.h = __builtin_amdgcn_cvt_pkrtz(a, b);
    return r.u;
}

__device__ __forceinline__ f32x4 mfma16(const unsigned a[4], const unsigned b[4], f32x4 c) {
    union { unsigned u[4]; f16x8 h; } A, B;
    A.u[0] = a[0]; A.u[1] = a[1]; A.u[2] = a[2]; A.u[3] = a[3];
    B.u[0] = b[0]; B.u[1] = b[1]; B.u[2] = b[2]; B.u[3] = b[3];
    return __builtin_amdgcn_mfma_f32_16x16x32_f16(A.h, B.h, c, 0, 0, 0);
}

__device__ __forceinline__ unsigned short f16b(float v) {
    union { _Float16 h; unsigned short s; } cv; cv.h = (_Float16)v; return cv.s;
}

// whQKV: f16 [384][128] (rows 0..127 pre-scaled by 1/sqrt(hd))
// whP  : f16 [128][128]
// biasT: f32 [wtype][head][i][j]  (rel-pos bias + shift mask + key-pad mask)
__global__ void prep2(const float* __restrict__ rpb,
                      const float* __restrict__ w_qkv,
                      const float* __restrict__ w_proj,
                      unsigned short* __restrict__ whQKV,
                      unsigned short* __restrict__ whP,
                      float* __restrict__ biasT)
{
    int idx = blockIdx.x * 256 + threadIdx.x;               // 131072 total
    if (idx < 49152) {
        float v = w_qkv[idx];
        if (idx < 16384) v *= SCALE_Q;                      // q rows 0..127
        whQKV[idx] = f16b(v);
    } else if (idx < 65536) {
        int j = idx - 49152;
        whP[j] = f16b(w_proj[j]);
    } else {
        int k = idx - 65536;                                // 65536 bias elems
        int j = k & 63, i = (k >> 6) & 63, h = (k >> 12) & 3, t = k >> 14;
        float v;
        if (j >= 49)      v = -1e30f;                       // key padding
        else if (i >= 49) v = 0.f;                          // query padding (don't care)
        else {
            int ri = i / 7, ci = i % 7, rj = j / 7, cj = j % 7;
            int rel = (ri - rj + 6) * 13 + (ci - cj + 6);
            v = rpb[rel * 4 + h];
            int gi = ((t & 2) ? (ri < 4 ? 1 : 2) : 0) * 3 + ((t & 1) ? (ci < 4 ? 1 : 2) : 0);
            int gj = ((t & 2) ? (rj < 4 ? 1 : 2) : 0) * 3 + ((t & 1) ? (cj < 4 ? 1 : 2) : 0);
            if (gi != gj) v -= 100.f;
        }
        biasT[k] = v;
    }
}

__global__ __launch_bounds__(256, 4)
void swin_msa_mfma2(const float* __restrict__ x,
                    const unsigned short* __restrict__ whQKV,
                    const unsigned short* __restrict__ whP,
                    const float* __restrict__ b_proj,
                    const float* __restrict__ biasT,
                    float* __restrict__ out)
{
    // Q,K staged f16 [tok 0..63][col 0..255] stride 264 halves; O overlays
    // the same buffer later at stride 136. 33792 B -> 4 blocks/CU.
    __shared__ __align__(16) unsigned short QKO[64 * 264];

    const int tid  = threadIdx.x;
    const int w    = tid >> 6;         // wave id (= head in attention)
    const int lane = tid & 63;
    const int c    = lane & 15;
    const int g    = lane >> 4;

    const int blk  = blockIdx.x;
    const int b    = blk >> 6;
    const int wIdx = blk & 63;
    const int wh   = wIdx >> 3, ww = wIdx & 7;
    const int wtype = ((wh == 7) ? 2 : 0) | ((ww == 7) ? 1 : 0);

    auto tokAddr = [&](int tok) {      // tok must be < 49
        int rr = tok / 7, cc = tok - rr * 7;
        int sh = wh * 7 + rr + 3; if (sh >= HWD) sh -= HWD;
        int sw = ww * 7 + cc + 3; if (sw >= HWD) sw -= HWD;
        return ((b * HWD + sh) * HWD + sw) * 128;
    };

    // ---- X fragments (A- and B-frag layouts are identical for X)
    unsigned xf[4][4][4];              // [tok-tile][kstep][word]
    #pragma unroll
    for (int nt = 0; nt < 4; ++nt) {
        int tok = nt * 16 + c; if (tok > 48) tok = 48;      // clamp pad rows
        const float* xr = x + tokAddr(tok) + g * 8;
        #pragma unroll
        for (int kk = 0; kk < 4; ++kk) {
            float4 lo = *(const float4*)(xr + kk * 32);
            float4 hi = *(const float4*)(xr + kk * 32 + 4);
            xf[nt][kk][0] = pkrtz(lo.x, lo.y);
            xf[nt][kk][1] = pkrtz(lo.z, lo.w);
            xf[nt][kk][2] = pkrtz(hi.x, hi.y);
            xf[nt][kk][3] = pkrtz(hi.z, hi.w);
        }
    }

    const int srcA  = c | ((lane & 16) << 1);  // lane (c, 2*(g&1))
    const int srcB  = srcA + 16;               // lane (c, 2*(g&1)+1)
    const bool hiSel = (lane & 32) != 0;       // g>>1 selects tile-pair member

    // ---- V (own head, cols 256+32w..+31): mfma(X,Wv) -> D[tok][d], then
    //      redistribute D->A-frag (A[m=d][k=tok]) fully in registers.
    unsigned vA[2][2][4];              // [vi(d-tile)][kv(tok-half)][word]
    {
        unsigned pkV[2][4][2];         // [vi][tok-tile][word]
        #pragma unroll
        for (int vi = 0; vi < 2; ++vi) {
            const int vt = 2 * w + vi;
            unsigned bf[4][4];
            const unsigned short* wr = whQKV + (256 + vt * 16 + c) * 128 + g * 8;
            #pragma unroll
            for (int kk = 0; kk < 4; ++kk) {
                uint4 v = *(const uint4*)(wr + kk * 32);
                bf[kk][0] = v.x; bf[kk][1] = v.y; bf[kk][2] = v.z; bf[kk][3] = v.w;
            }
            #pragma unroll
            for (int mt = 0; mt < 4; ++mt) {
                f32x4 acc = {0.f, 0.f, 0.f, 0.f};
                #pragma unroll
                for (int kk = 0; kk < 4; ++kk) acc = mfma16(xf[mt][kk], bf[kk], acc);
                pkV[vi][mt][0] = pkrtz(acc[0], acc[1]);     // toks 4g'+0,1
                pkV[vi][mt][1] = pkrtz(acc[2], acc[3]);     // toks 4g'+2,3
            }
        }
        #pragma unroll
        for (int vi = 0; vi < 2; ++vi)
            #pragma unroll
            for (int kv = 0; kv < 2; ++kv)
                #pragma unroll
                for (int p = 0; p < 2; ++p) {
                    unsigned lo0 = __shfl(pkV[vi][2 * kv][p],     srcA);
                    unsigned hi0 = __shfl(pkV[vi][2 * kv + 1][p], srcA);
                    vA[vi][kv][p] = hiSel ? hi0 : lo0;
                    unsigned lo1 = __shfl(pkV[vi][2 * kv][p],     srcB);
                    unsigned hi1 = __shfl(pkV[vi][2 * kv + 1][p], srcB);
                    vA[vi][kv][2 + p] = hiSel ? hi1 : lo1;
                }
    }

    // ---- Q,K (cols 0..255): mfma(W,X) -> D[col][tok] -> row-major LDS store
    #pragma unroll
    for (int mi = 0; mi < 4; ++mi) {
        const int mt = 4 * w + mi;     // q:0-7, k:8-15 (q pre-scaled in weights)
        unsigned af[4][4];
        const unsigned short* wr = whQKV + (mt * 16 + c) * 128 + g * 8;
        #pragma unroll
        for (int kk = 0; kk < 4; ++kk) {
            uint4 v = *(const uint4*)(wr + kk * 32);
            af[kk][0] = v.x; af[kk][1] = v.y; af[kk][2] = v.z; af[kk][3] = v.w;
        }
        #pragma unroll
        for (int nt = 0; nt < 4; ++nt) {
            f32x4 acc = {0.f, 0.f, 0.f, 0.f};
            #pragma unroll
            for (int kk = 0; kk < 4; ++kk) acc = mfma16(af[kk], xf[nt][kk], acc);
            *(uint2*)&QKO[(nt * 16 + c) * 264 + mt * 16 + 4 * g] =
                make_uint2(pkrtz(acc[0], acc[1]), pkrtz(acc[2], acc[3]));
        }
    }
    __syncthreads();

    // ================= attention (wave = head h), per-i-tile fused =========
    const int h = w;
    unsigned kA[4][4];
    #pragma unroll
    for (int mt = 0; mt < 4; ++mt) {   // A = K[j][d]
        uint4 v = *(const uint4*)&QKO[(mt * 16 + c) * 264 + 128 + h * 32 + g * 8];
        kA[mt][0] = v.x; kA[mt][1] = v.y; kA[mt][2] = v.z; kA[mt][3] = v.w;
    }
    const float* bT = biasT + (wtype * 4 + h) * 4096;       // [i][j]
    f32x4 O[4][2];
    #pragma unroll
    for (int nt = 0; nt < 4; ++nt) {
        O[nt][0] = (f32x4){0.f, 0.f, 0.f, 0.f};
        O[nt][1] = (f32x4){0.f, 0.f, 0.f, 0.f};
    }

    #pragma unroll
    for (int nt = 0; nt < 4; ++nt) {
        unsigned qB[4];                // B = Q^T: B[d][i]
        { uint4 v = *(const uint4*)&QKO[(nt * 16 + c) * 264 + h * 32 + g * 8];
          qB[0] = v.x; qB[1] = v.y; qB[2] = v.z; qB[3] = v.w; }
        f32x4 S[4];                    // S^T: lane j=16mt+4g+r, i=16nt+c
        #pragma unroll
        for (int mt = 0; mt < 4; ++mt) {
            float4 b4 = *(const float4*)&bT[(nt * 16 + c) * 64 + mt * 16 + 4 * g];
            f32x4 C = { b4.x, b4.y, b4.z, b4.w };           // bias as MFMA C-operand
            S[mt] = mfma16(kA[mt], qB, C);
        }
        // softmax over j (16 in-lane + 2 butterflies)
        float m = -1e30f;
        #pragma unroll
        for (int mt = 0; mt < 4; ++mt)
            #pragma unroll
            for (int r = 0; r < 4; ++r) m = fmaxf(m, S[mt][r]);
        m = fmaxf(m, __shfl_xor(m, 16));
        m = fmaxf(m, __shfl_xor(m, 32));
        float s = 0.f;
        #pragma unroll
        for (int mt = 0; mt < 4; ++mt)
            #pragma unroll
            for (int r = 0; r < 4; ++r) { float e = __expf(S[mt][r] - m); S[mt][r] = e; s += e; }
        s += __shfl_xor(s, 16);
        s += __shfl_xor(s, 32);
        const float iv = 1.0f / s;
        // P -> B-frag via shuffles, PV mfma
        unsigned pk[4][2];
        #pragma unroll
        for (int mt = 0; mt < 4; ++mt) {
            pk[mt][0] = pkrtz(S[mt][0] * iv, S[mt][1] * iv);
            pk[mt][1] = pkrtz(S[mt][2] * iv, S[mt][3] * iv);
        }
        #pragma unroll
        for (int kk = 0; kk < 2; ++kk) {
            unsigned pB[4];
            #pragma unroll
            for (int p = 0; p < 2; ++p) {
                unsigned lo0 = __shfl(pk[2 * kk][p],     srcA);
                unsigned hi0 = __shfl(pk[2 * kk + 1][p], srcA);
                pB[p] = hiSel ? hi0 : lo0;
                unsigned lo1 = __shfl(pk[2 * kk][p],     srcB);
                unsigned hi1 = __shfl(pk[2 * kk + 1][p], srcB);
                pB[2 + p] = hiSel ? hi1 : lo1;
            }
            #pragma unroll
            for (int dn = 0; dn < 2; ++dn)
                O[nt][dn] = mfma16(vA[dn][kk], pB, O[nt][dn]);
        }
    }
    __syncthreads();    // all QKO reads done -> safe to overlay O

    // O store: lane i = nt*16+c, d = h*32+dn*16+4g..+3 -> [tok][d] stride 136
    #pragma unroll
    for (int nt = 0; nt < 4; ++nt)
        #pragma unroll
        for (int dn = 0; dn < 2; ++dn)
            *(uint2*)&QKO[(nt * 16 + c) * 136 + h * 32 + dn * 16 + 4 * g] =
                make_uint2(pkrtz(O[nt][dn][0], O[nt][dn][1]),
                           pkrtz(O[nt][dn][2], O[nt][dn][3]));
    __syncthreads();

    // ================= out-proj: OUT = O @ Wproj^T + b =================
    int taddr[4];
    #pragma unroll
    for (int nt = 0; nt < 4; ++nt) {
        int tok = nt * 16 + c;
        taddr[nt] = (tok < 49) ? tokAddr(tok) : -1;
    }
    unsigned oB[4][4][4];              // B[k=d][n=i] from O[i][d]
    #pragma unroll
    for (int nt = 0; nt < 4; ++nt)
        #pragma unroll
        for (int kk = 0; kk < 4; ++kk) {
            uint4 v = *(const uint4*)&QKO[(nt * 16 + c) * 136 + kk * 32 + g * 8];
            oB[nt][kk][0] = v.x; oB[nt][kk][1] = v.y; oB[nt][kk][2] = v.z; oB[nt][kk][3] = v.w;
        }
    #pragma unroll
    for (int mi = 0; mi < 2; ++mi) {
        const int mt = 2 * w + mi;                          // out-col tile 0..7
        unsigned aW[4][4];
        const unsigned short* wr = whP + (mt * 16 + c) * 128 + g * 8;
        #pragma unroll
        for (int kk = 0; kk < 4; ++kk) {
            uint4 v = *(const uint4*)(wr + kk * 32);
            aW[kk][0] = v.x; aW[kk][1] = v.y; aW[kk][2] = v.z; aW[kk][3] = v.w;
        }
        float4 bias4 = *(const float4*)(b_proj + mt * 16 + 4 * g);
        #pragma unroll
        for (int nt = 0; nt < 4; ++nt) {
            f32x4 acc = {0.f, 0.f, 0.f, 0.f};
            #pragma unroll
            for (int kk = 0; kk < 4; ++kk) acc = mfma16(aW[kk], oB[nt][kk], acc);
            if (taddr[nt] >= 0) {
                float4 o = make_float4(acc[0] + bias4.x, acc[1] + bias4.y,
                                       acc[2] + bias4.z, acc[3] + bias4.w);
                *(float4*)(out + taddr[nt] + mt * 16 + 4 * g) = o;
            }
        }
    }
}

extern "C" void kernel_launch(void* const* d_in, const int* in_sizes, int n_in,
                              void* d_out, int out_size, void* d_ws, size_t ws_size,
                              hipStream_t stream) {
    const float* x     = (const float*)d_in[0];
    const float* rpb   = (const float*)d_in[1];
    const float* wqkv  = (const float*)d_in[2];
    const float* wproj = (const float*)d_in[3];
    const float* bproj = (const float*)d_in[4];
    float* outp = (float*)d_out;

    unsigned short* whQKV = (unsigned short*)d_ws;          // 49152 halves
    unsigned short* whP   = whQKV + 49152;                  // 16384 halves
    float* biasT = (float*)(whP + 16384);                   // 65536 f32 (offset 128KB)

    prep2<<<512, 256, 0, stream>>>(rpb, wqkv, wproj, whQKV, whP, biasT);
    swin_msa_mfma2<<<32 * 64, 256, 0, stream>>>(x, whQKV, whP, bproj, biasT, outp);
}